// Round 4
// baseline (641.432 us; speedup 1.0000x reference)
//
#include <hip/hip_runtime.h>
#include <hip/hip_bf16.h>
#include <cstdint>
#include <cstddef>

#define N_NODES 20000
#define F_IN    2000
#define H_DIM   128
#define L_DIM   15
#define K_PAD   2048      // padded K for B (w1r) layout
#define N1      512       // 4 hops * 128
#define BM      128
#define BN      128
#define BK      32
#define I_TILES 157       // ceil(20000/128)

typedef __attribute__((ext_vector_type(4))) float f32x4;
typedef __attribute__((ext_vector_type(8))) short s16x8;
typedef __attribute__((ext_vector_type(8))) unsigned short u16x8;
typedef __attribute__((ext_vector_type(4))) unsigned int u32x4;

__device__ __forceinline__ unsigned short f2bf(float f) {
  unsigned int u = __float_as_uint(f);
  u += 0x7fff + ((u >> 16) & 1);   // RNE
  return (unsigned short)(u >> 16);
}

// pack 2 floats -> 2 bf16 in one u32 (low = a), RNE via packed cvt
__device__ __forceinline__ unsigned int pkbf(float a, float b) {
  union { __hip_bfloat162 h; unsigned int u; } cv;
  cv.h = __float22bfloat162_rn(make_float2(a, b));
  return cv.u;
}

// unpack u32 (2 bf16) -> float2 (x = low half)
__device__ __forceinline__ float2 bf2f(unsigned int u) {
  float2 r;
  r.x = __uint_as_float(u << 16);
  r.y = __uint_as_float(u & 0xffff0000u);
  return r;
}

// ---- W1 [8000][128] -> bf16 B^T [512][2048] via coalesced read + LDS transpose ----
__global__ __launch_bounds__(256) void k_cvt_w1(const float* __restrict__ W1,
                                                unsigned short* __restrict__ bt) {
  __shared__ unsigned short tile[128 * 67];
  const int hop = blockIdx.x >> 5;
  const int k0  = (blockIdx.x & 31) * 64;
  const int t = threadIdx.x;
#pragma unroll
  for (int it = 0; it < 8; ++it) {
    int f4 = it * 256 + t;
    int r  = f4 >> 5;
    int c4 = f4 & 31;
    int k = k0 + r;
    float4 v = make_float4(0.f, 0.f, 0.f, 0.f);
    if (k < F_IN) v = *(const float4*)(W1 + (size_t)(hop * F_IN + k) * H_DIM + c4 * 4);
    tile[(c4 * 4 + 0) * 67 + r] = f2bf(v.x);
    tile[(c4 * 4 + 1) * 67 + r] = f2bf(v.y);
    tile[(c4 * 4 + 2) * 67 + r] = f2bf(v.z);
    tile[(c4 * 4 + 3) * 67 + r] = f2bf(v.w);
  }
  __syncthreads();
  const int c = t >> 1, kh = (t & 1) * 32;
  unsigned short* dst = bt + (size_t)(hop * 128 + c) * K_PAD + k0 + kh;
  const unsigned short* srcp = tile + c * 67 + kh;
#pragma unroll
  for (int q = 0; q < 4; ++q) {
    u16x8 o;
#pragma unroll
    for (int e = 0; e < 8; ++e) o[e] = srcp[q * 8 + e];
    *(u16x8*)(dst + q * 8) = o;
  }
}

// ---- K-split bf16 MFMA GEMM with fused fp32->bf16 A conversion ----
// grid = 1280: xcd=b&7, mid=(b>>3)&7 -> {j_tile=mid&3, ks=mid>>2}, i_tile=(b&7)+8*(b>>6)
// All 8 (j,ks) blocks of an i_tile share b mod 8 -> same XCD -> A rows L2-shared.
__global__ __launch_bounds__(256) void k_gemm1(const float* __restrict__ X,
                                               const unsigned short* __restrict__ B,
                                               float* __restrict__ C0,
                                               float* __restrict__ C1) {
  __shared__ unsigned short As[BM * BK];   // bf16 after in-register cvt
  __shared__ unsigned short Bs[BN * BK];
  const int b = blockIdx.x;
  const int i_tile = (b & 7) + 8 * (b >> 6);
  const int mid = (b >> 3) & 7;
  const int j_tile = mid & 3;
  const int ks = mid >> 2;
  if (i_tile >= I_TILES) return;
  const int rowA0 = i_tile * BM;
  const int colB0 = j_tile * BN;
  const int tid  = threadIdx.x;
  const int lane = tid & 63;
  const int wave = tid >> 6;
  const int wm = (wave >> 1) * 64;
  const int wn = (wave & 1) * 64;
  const int quad = lane >> 4;
  const int l15  = lane & 15;
  f32x4 acc[4][4] = {};

  const int kend = ks ? F_IN : 1024;       // ks=1 stops at 2000 (A has no pad)
  for (int kt = ks * 1024; kt < kend; kt += BK) {
    // B: async global->LDS (w1r is zero-padded to 2048, safe at the boundary)
#pragma unroll
    for (int r = 0; r < 2; ++r) {
      int c = r * 256 + tid;
      int row = c >> 2;
      int kc = (c & 3) * 8;
      const unsigned short* gb = B + (size_t)(colB0 + row) * K_PAD + kt + kc;
      __builtin_amdgcn_global_load_lds((const __attribute__((address_space(1))) void*)gb,
                                       (__attribute__((address_space(3))) void*)(Bs + c * 8),
                                       16, 0, 0);
    }
    // A: guarded fp32 loads -> packed bf16 -> LDS (chunk = 8 consecutive k)
#pragma unroll
    for (int r = 0; r < 2; ++r) {
      int c = r * 256 + tid;
      int row = c >> 2;
      int kc = (c & 3) * 8;
      int grow = rowA0 + row;
      int gk = kt + kc;
      float4 va = make_float4(0.f, 0.f, 0.f, 0.f);
      float4 vb = make_float4(0.f, 0.f, 0.f, 0.f);
      if (grow < N_NODES && gk < F_IN) {   // F_IN%8==0 -> all-or-none per chunk
        const float* p = X + (size_t)grow * F_IN + gk;
        va = *(const float4*)p;
        vb = *(const float4*)(p + 4);
      }
      u32x4 w;
      w.x = pkbf(va.x, va.y); w.y = pkbf(va.z, va.w);
      w.z = pkbf(vb.x, vb.y); w.w = pkbf(vb.z, vb.w);
      *(u32x4*)(As + (size_t)c * 8) = w;
    }
    __syncthreads();
    s16x8 af[4], bfr[4];
#pragma unroll
    for (int i = 0; i < 4; ++i)
      af[i] = *(const s16x8*)(As + (wm + i * 16 + l15) * BK + quad * 8);
#pragma unroll
    for (int j = 0; j < 4; ++j)
      bfr[j] = *(const s16x8*)(Bs + (wn + j * 16 + l15) * BK + quad * 8);
#pragma unroll
    for (int i = 0; i < 4; ++i)
#pragma unroll
      for (int j = 0; j < 4; ++j)
        acc[i][j] = __builtin_amdgcn_mfma_f32_16x16x32_bf16(af[i], bfr[j], acc[i][j], 0, 0, 0);
    __syncthreads();
  }

  float* Cp = ks ? C1 : C0;
#pragma unroll
  for (int i = 0; i < 4; ++i) {
    int row0 = rowA0 + wm + i * 16 + quad * 4;
#pragma unroll
    for (int j = 0; j < 4; ++j) {
      int col = colB0 + wn + j * 16 + l15;
#pragma unroll
      for (int r = 0; r < 4; ++r) {
        int row = row0 + r;
        if (row < N_NODES) Cp[(size_t)row * N1 + col] = acc[i][j][r];
      }
    }
  }
}

// ---- combine K-split partials in-place: C0 += C1 (cols<384); cols>=384 -> bf16 Yb3 ----
__global__ __launch_bounds__(256) void k_comb(float* __restrict__ C0,
                                              const float* __restrict__ C1,
                                              unsigned short* __restrict__ Yb3) {
  unsigned int t = blockIdx.x * 256u + threadIdx.x;   // 20000*128 threads
  unsigned int row = t >> 7;
  unsigned int c4 = (t & 127u) * 4u;
  size_t idx = (size_t)row * N1 + c4;
  float4 a = *(const float4*)(C0 + idx);
  float4 b = *(const float4*)(C1 + idx);
  float4 s = make_float4(a.x + b.x, a.y + b.y, a.z + b.z, a.w + b.w);
  if (c4 < 384) {
    *(float4*)(C0 + idx) = s;
  } else {
    unsigned int u0 = pkbf(s.x, s.y), u1 = pkbf(s.z, s.w);
    *(uint2*)(Yb3 + (size_t)row * H_DIM + (c4 - 384)) = make_uint2(u0, u1);
  }
}

// ---- CSR build ----
__global__ __launch_bounds__(256) void k_hist(const int* __restrict__ dst,
                                              int* __restrict__ deg, int E) {
  int i = blockIdx.x * 256 + threadIdx.x;
  int e = i * 4;
  if (e + 4 <= E) {
    int4 d4 = *(const int4*)(dst + e);
    atomicAdd(&deg[d4.x], 1); atomicAdd(&deg[d4.y], 1);
    atomicAdd(&deg[d4.z], 1); atomicAdd(&deg[d4.w], 1);
  } else {
    for (; e < E; ++e) atomicAdd(&deg[dst[e]], 1);
  }
}

__global__ __launch_bounds__(1024) void k_scan(const int* __restrict__ deg,
                                               int* __restrict__ rowStart,
                                               int* __restrict__ cursor) {
  __shared__ int sums[1024];
  const int t = threadIdx.x;
  const int chunk = (N_NODES + 1023) / 1024;
  int lo = t * chunk;
  int hi = lo + chunk; if (hi > N_NODES) hi = N_NODES;
  int s = 0;
  for (int i = lo; i < hi; ++i) s += deg[i];
  sums[t] = s;
  __syncthreads();
  for (int off = 1; off < 1024; off <<= 1) {
    int v = sums[t];
    int u = (t >= off) ? sums[t - off] : 0;
    __syncthreads();
    sums[t] = v + u;
    __syncthreads();
  }
  int run = sums[t] - s;
  for (int i = lo; i < hi; ++i) {
    rowStart[i] = run; cursor[i] = run; run += deg[i];
  }
  if (t == 1023) rowStart[N_NODES] = run;
}

__global__ __launch_bounds__(256) void k_scatter(const int* __restrict__ src,
                                                 const int* __restrict__ dst,
                                                 const float* __restrict__ w,
                                                 int* cursor,
                                                 int2* __restrict__ eSW, int E) {
  int e = blockIdx.x * 256 + threadIdx.x;
  if (e >= E) return;
  int p = atomicAdd(&cursor[dst[e]], 1);
  eSW[p] = make_int2(src[e], __float_as_int(w[e]));
}

// ---- pull-propagation: bf16 gather source, fp32 accumulate + fp32 addend ----
// mode 0: out = bf16(addv + acc)   mode 1: out = fp32 relu(BN(addv + acc + b1))
__global__ __launch_bounds__(256) void k_prop128b(const int* __restrict__ rowStart,
    const int2* __restrict__ eSW,
    const unsigned short* __restrict__ gsrc,   // bf16 [N_NODES][128]
    const float* __restrict__ addv, int addStride, int addOff,
    unsigned short* __restrict__ outb, float* __restrict__ outf,
    const float* __restrict__ b1, const float* __restrict__ gamma,
    const float* __restrict__ beta, const float* __restrict__ mean,
    const float* __restrict__ var, int doBN) {
  const int lane = threadIdx.x & 63;
  const int d = blockIdx.x * 4 + (threadIdx.x >> 6);
  const int s0 = rowStart[d], s1 = rowStart[d + 1];
  const int c2 = lane * 2;
  float ax = 0.f, ay = 0.f;
  int j = s0;
  for (; j + 8 <= s1; j += 8) {
    int2 e0 = eSW[j],     e1 = eSW[j + 1], e2 = eSW[j + 2], e3 = eSW[j + 3];
    int2 e4 = eSW[j + 4], e5 = eSW[j + 5], e6 = eSW[j + 6], e7 = eSW[j + 7];
    unsigned int g0 = *(const unsigned int*)(gsrc + (size_t)e0.x * H_DIM + c2);
    unsigned int g1 = *(const unsigned int*)(gsrc + (size_t)e1.x * H_DIM + c2);
    unsigned int g2 = *(const unsigned int*)(gsrc + (size_t)e2.x * H_DIM + c2);
    unsigned int g3 = *(const unsigned int*)(gsrc + (size_t)e3.x * H_DIM + c2);
    unsigned int g4 = *(const unsigned int*)(gsrc + (size_t)e4.x * H_DIM + c2);
    unsigned int g5 = *(const unsigned int*)(gsrc + (size_t)e5.x * H_DIM + c2);
    unsigned int g6 = *(const unsigned int*)(gsrc + (size_t)e6.x * H_DIM + c2);
    unsigned int g7 = *(const unsigned int*)(gsrc + (size_t)e7.x * H_DIM + c2);
    float2 v0 = bf2f(g0), v1 = bf2f(g1), v2 = bf2f(g2), v3 = bf2f(g3);
    float2 v4 = bf2f(g4), v5 = bf2f(g5), v6 = bf2f(g6), v7 = bf2f(g7);
    float w0 = __int_as_float(e0.y), w1 = __int_as_float(e1.y);
    float w2 = __int_as_float(e2.y), w3 = __int_as_float(e3.y);
    float w4 = __int_as_float(e4.y), w5 = __int_as_float(e5.y);
    float w6 = __int_as_float(e6.y), w7 = __int_as_float(e7.y);
    ax = fmaf(w0, v0.x, ax); ay = fmaf(w0, v0.y, ay);
    ax = fmaf(w1, v1.x, ax); ay = fmaf(w1, v1.y, ay);
    ax = fmaf(w2, v2.x, ax); ay = fmaf(w2, v2.y, ay);
    ax = fmaf(w3, v3.x, ax); ay = fmaf(w3, v3.y, ay);
    ax = fmaf(w4, v4.x, ax); ay = fmaf(w4, v4.y, ay);
    ax = fmaf(w5, v5.x, ax); ay = fmaf(w5, v5.y, ay);
    ax = fmaf(w6, v6.x, ax); ay = fmaf(w6, v6.y, ay);
    ax = fmaf(w7, v7.x, ax); ay = fmaf(w7, v7.y, ay);
  }
  for (; j < s1; ++j) {
    int2 e = eSW[j];
    float2 v = bf2f(*(const unsigned int*)(gsrc + (size_t)e.x * H_DIM + c2));
    float w = __int_as_float(e.y);
    ax = fmaf(w, v.x, ax); ay = fmaf(w, v.y, ay);
  }
  float2 av = *(const float2*)(addv + (size_t)d * addStride + addOff + c2);
  float r0 = av.x + ax, r1 = av.y + ay;
  if (doBN) {
    float2 bb = *(const float2*)(b1 + c2);
    float2 gg = *(const float2*)(gamma + c2);
    float2 be = *(const float2*)(beta + c2);
    float2 mm = *(const float2*)(mean + c2);
    float2 vv = *(const float2*)(var + c2);
    r0 = (r0 + bb.x - mm.x) * rsqrtf(vv.x + 1e-3f) * gg.x + be.x;
    r1 = (r1 + bb.y - mm.y) * rsqrtf(vv.y + 1e-3f) * gg.y + be.y;
    r0 = r0 > 0.f ? r0 : 0.f;
    r1 = r1 > 0.f ? r1 : 0.f;
    *(float2*)(outf + (size_t)d * H_DIM + c2) = make_float2(r0, r1);
  } else {
    *(unsigned int*)(outb + (size_t)d * H_DIM + c2) = pkbf(r0, r1);
  }
}

// ---- Y2[20000][60] = H @ W2 (4 hop-blocks of [128][15]); fp32 ----
__global__ __launch_bounds__(256) void k_gemm2(const float* __restrict__ Hh,
                                               const float* __restrict__ W2,
                                               float* __restrict__ Y2) {
  __shared__ float w2s[512 * 15];
  for (int i = threadIdx.x; i < 512 * 15; i += 256) w2s[i] = W2[i];
  __syncthreads();
  const int c = threadIdx.x & 63;
  const int d = blockIdx.x * 4 + (threadIdx.x >> 6);
  if (c >= 60 || d >= N_NODES) return;
  const int hop = c / 15, j = c % 15;
  const float4* hr4 = (const float4*)(Hh + (size_t)d * H_DIM);
  float acc = 0.f;
#pragma unroll 8
  for (int k4 = 0; k4 < 32; ++k4) {
    float4 h = hr4[k4];
    const float* wp = w2s + ((hop << 7) + k4 * 4) * 15 + j;
    acc = fmaf(h.x, wp[0],  acc);
    acc = fmaf(h.y, wp[15], acc);
    acc = fmaf(h.z, wp[30], acc);
    acc = fmaf(h.w, wp[45], acc);
  }
  Y2[(size_t)d * 60 + c] = acc;
}

// ---- pull-propagation, 15-wide fp32 ----
__global__ __launch_bounds__(256) void k_prop15(const int* __restrict__ rowStart,
    const int2* __restrict__ eSW,
    const float* __restrict__ in, int inStride, int inOff,
    const float* __restrict__ addv, int addStride, int addOff,
    const float* __restrict__ bias, float* __restrict__ out) {
  const int f = threadIdx.x & 15;
  const int d = blockIdx.x * 16 + (threadIdx.x >> 4);
  if (f >= 15) return;
  const int s0 = rowStart[d], s1 = rowStart[d + 1];
  float acc = 0.f;
  int j = s0;
  for (; j + 4 <= s1; j += 4) {
    int2 e0 = eSW[j], e1 = eSW[j + 1], e2 = eSW[j + 2], e3 = eSW[j + 3];
    float v0 = in[(size_t)e0.x * inStride + inOff + f];
    float v1 = in[(size_t)e1.x * inStride + inOff + f];
    float v2 = in[(size_t)e2.x * inStride + inOff + f];
    float v3 = in[(size_t)e3.x * inStride + inOff + f];
    acc = fmaf(__int_as_float(e0.y), v0, acc);
    acc = fmaf(__int_as_float(e1.y), v1, acc);
    acc = fmaf(__int_as_float(e2.y), v2, acc);
    acc = fmaf(__int_as_float(e3.y), v3, acc);
  }
  for (; j < s1; ++j) {
    int2 e = eSW[j];
    acc = fmaf(__int_as_float(e.y), in[(size_t)e.x * inStride + inOff + f], acc);
  }
  float b = bias ? bias[f] : 0.f;
  out[(size_t)d * 15 + f] = addv[(size_t)d * addStride + addOff + f] + acc + b;
}

extern "C" void kernel_launch(void* const* d_in, const int* in_sizes, int n_in,
                              void* d_out, int out_size, void* d_ws, size_t ws_size,
                              hipStream_t stream) {
  const float* x     = (const float*)d_in[0];
  const int*   esrc  = (const int*)d_in[1];
  const int*   edst  = (const int*)d_in[2];
  const float* ew    = (const float*)d_in[3];
  const float* W1    = (const float*)d_in[4];
  const float* b1    = (const float*)d_in[5];
  const float* gamma = (const float*)d_in[6];
  const float* beta  = (const float*)d_in[7];
  const float* mmean = (const float*)d_in[8];
  const float* mvar  = (const float*)d_in[9];
  const float* W2    = (const float*)d_in[10];
  const float* b2    = (const float*)d_in[11];
  const int E = in_sizes[1];
  char* ws = (char*)d_ws;

  // workspace layout (94.5 MB total)
  float*          C0   = (float*)(ws);                     // 40,960,000  (becomes Y after k_comb)
  float*          C1   = (float*)(ws + 40960000);          // 40,960,000  (dead after k_comb)
  unsigned short* Yb3  = (unsigned short*)(ws + 81920000); //  5,120,000  bf16 y3 slice
  unsigned short* w1r  = (unsigned short*)(ws + 87040000); //  2,097,152
  int2*           eSW  = (int2*)(ws + 89137152);           //  5,120,000
  int*            deg      = (int*)(ws + 94257152);        //     80,128
  int*            rowStart = (int*)(ws + 94337280);        //     80,128
  int*            cursor   = (int*)(ws + 94417408);        //     80,128
  // overlays on C1 region (C1 dead after k_comb)
  unsigned short* P   = (unsigned short*)(ws + 40960000);  //  5,120,000  bf16
  unsigned short* Q   = (unsigned short*)(ws + 46080000);  //  5,120,000  bf16
  float*          Hb  = (float*)(ws + 51200000);           // 10,240,000
  float*          Y2  = (float*)(ws + 61440000);           //  4,800,000
  float*          zP  = (float*)(ws + 66240000);           //  1,200,000
  float*          zQ  = (float*)(ws + 67440000);           //  1,200,000
  float*          Y   = C0;
  float*          zout = (float*)d_out;

  // CSR by dst (reused by all 6 propagations)
  hipMemsetAsync(deg, 0, N_NODES * sizeof(int), stream);
  k_hist<<<(E / 4 + 255) / 256 + 1, 256, 0, stream>>>(edst, deg, E);
  k_scan<<<1, 1024, 0, stream>>>(deg, rowStart, cursor);
  k_scatter<<<(E + 255) / 256, 256, 0, stream>>>(esrc, edst, ew, cursor, eSW, E);

  // GEMM1 (fused cvt, K-split 2): C0/C1 partials, then combine -> Y fp32 + Yb3 bf16
  k_cvt_w1<<<128, 256, 0, stream>>>(W1, w1r);
  k_gemm1<<<1280, 256, 0, stream>>>(x, w1r, C0, C1);
  k_comb<<<(N_NODES * 128) / 256, 256, 0, stream>>>(C0, C1, Yb3);

  // conv1 hops: h = BN(relu-side) of y0 + A(y1 + A(y2 + A*y3)); P,Q bf16 L2-resident
  k_prop128b<<<N_NODES / 4, 256, 0, stream>>>(rowStart, eSW, Yb3, Y, N1, 2 * H_DIM,
                                              P, nullptr, b1, gamma, beta, mmean, mvar, 0);
  k_prop128b<<<N_NODES / 4, 256, 0, stream>>>(rowStart, eSW, P, Y, N1, 1 * H_DIM,
                                              Q, nullptr, b1, gamma, beta, mmean, mvar, 0);
  k_prop128b<<<N_NODES / 4, 256, 0, stream>>>(rowStart, eSW, Q, Y, N1, 0,
                                              nullptr, Hb, b1, gamma, beta, mmean, mvar, 1);

  // GEMM2 + conv2 hops: z = u0 + A(u1 + A(u2 + A*u3)) + b2
  k_gemm2<<<N_NODES / 4, 256, 0, stream>>>(Hb, W2, Y2);
  k_prop15<<<N_NODES / 16, 256, 0, stream>>>(rowStart, eSW, Y2, 60, 45, Y2, 60, 30, nullptr, zP);
  k_prop15<<<N_NODES / 16, 256, 0, stream>>>(rowStart, eSW, zP, 15, 0, Y2, 60, 15, nullptr, zQ);
  k_prop15<<<N_NODES / 16, 256, 0, stream>>>(rowStart, eSW, zQ, 15, 0, Y2, 60, 0, b2, zout);
}